// Round 10
// baseline (132.927 us; speedup 1.0000x reference)
//
#include <hip/hip_runtime.h>
#include <hip/hip_bf16.h>

#define L 2048
#define HD 1024   // H*D
#define NB 8      // batch
#define NT 32     // K tiles of BK=64
#define PROW 4096 // p8 row length

using f32x4 = __attribute__((ext_vector_type(4))) float;
using fl4   = __attribute__((ext_vector_type(4))) float;
using s16x8 = __attribute__((ext_vector_type(8))) short;

__device__ __forceinline__ short f2bf(float f) {
    __hip_bfloat16 h = __float2bfloat16(f);
    short s;
    __builtin_memcpy(&s, &h, 2);
    return s;
}

__device__ __forceinline__ void gload_lds16(const void* g, void* l) {
    __builtin_amdgcn_global_load_lds(
        (const __attribute__((address_space(1))) unsigned int*)g,
        (__attribute__((address_space(3))) unsigned int*)l, 16, 0, 0);
}

// ---- fused: p8[s][x] = bf16(p[x+s]) (blocks 0..127) ; z (block 128) ----
__global__ __launch_bounds__(256) void pb_prep(const float* __restrict__ w,
                                               short* __restrict__ p8,
                                               float* __restrict__ z) {
    __shared__ float part[256];
    __shared__ float S[L];
    const int t = threadIdx.x;
    if (blockIdx.x < 128) {
        int idx = blockIdx.x * 256 + t;
        int s = idx >> 12;
        int x = idx & (PROW - 1);
        int k = x + s;
        short val = 0;
        if (k <= 4094) {
            int d = k - 2047; d = d < 0 ? -d : d;
            val = f2bf(w[d]);
        }
        p8[idx] = val;
    } else {
        float loc[8]; float s = 0.f;
        #pragma unroll
        for (int i = 0; i < 8; ++i) { loc[i] = w[t * 8 + i]; s += loc[i]; }
        part[t] = s;
        __syncthreads();
        if (t == 0) {
            float a = 0.f;
            for (int i = 0; i < 256; ++i) { float tmp = part[i]; part[i] = a; a += tmp; }
        }
        __syncthreads();
        float a = part[t];
        #pragma unroll
        for (int i = 0; i < 8; ++i) { a += loc[i]; S[t * 8 + i] = a; }
        __syncthreads();
        const float w0 = S[0];
        #pragma unroll
        for (int i = 0; i < 8; ++i) {
            int j = t * 8 + i;
            z[j] = S[j] + S[2047 - j] - w0;
        }
    }
}

// ---- vt: linear chunk layout. chunk[((n*NT+kk)*1024 + c)*8 + h] (16B) =
//      bf16(v[n][kk*64 + h*8 + j][c]), j=0..7 ----
__global__ __launch_bounds__(256) void pb_vtile(const float* __restrict__ v,
                                                s16x8* __restrict__ vt) {
    // Ts: (c,l) at c*64 + ((lblk ^ ((c>>2)&7))<<3) + lsub  (slot swizzle)
    __shared__ __align__(16) short Ts[256 * 64];   // 32 KB
    const int kk = blockIdx.x, cg4 = blockIdx.y, n = blockIdx.z;
    const int l0 = kk * 64, c0 = cg4 * 256;
    const int t = threadIdx.x;
    const float* vn = v + (size_t)n * L * HD;

    #pragma unroll
    for (int i = 0; i < 16; ++i) {
        int unit = i * 256 + t;          // 4096 units = 64 l x 64 quads
        int l = unit >> 6, cq = unit & 63;
        fl4 x = *(const fl4*)&vn[(size_t)(l0 + l) * HD + c0 + cq * 4];
        int lsub = l & 7, lblk = l >> 3;
        #pragma unroll
        for (int j = 0; j < 4; ++j) {
            int c = cq * 4 + j;
            Ts[c * 64 + ((lblk ^ ((c >> 2) & 7)) << 3) + lsub] = f2bf(x[j]);
        }
    }
    __syncthreads();

    s16x8* outp = vt + ((size_t)(n * NT + kk) * 1024 + c0) * 8;
    #pragma unroll
    for (int i2 = 0; i2 < 8; ++i2) {
        int ci = i2 * 256 + t;           // 2048 chunks (256 c x 8 h)
        int c = ci >> 3, h = ci & 7;
        int slot = h ^ ((c >> 2) & 7);
        outp[ci] = *(const s16x8*)&Ts[c * 64 + slot * 8];
    }
}

// ---- main GEMM: 128x128 tile, 4 waves, per-wave private LDS dbuf,
//      A direct from L1-resident p8, ZERO barriers in the K-loop ----
__global__ __launch_bounds__(256, 2) void pb_gemmw(const short* __restrict__ p8,
                                                   const short* __restrict__ vt,
                                                   float* __restrict__ out) {
    __shared__ __align__(16) short lds_[32768];  // 64 KB: 4 waves x (2 x 8 KB)

    const int bid = blockIdx.x;
    // XCD affinity: XCD = bid%8 = cm; all jm,n peers of one cm share an XCD
    const int cm = bid & 7;
    const int n  = (bid >> 3) & 7;
    const int jm = bid >> 6;
    const int j0 = jm * 128;
    const int c0 = cm * 128;

    const int t = threadIdx.x;
    const int lane = t & 63;
    const int w = t >> 6;                 // wave 0..3
    const int wr = w >> 1, wc = w & 1;    // 2x2 wave grid, 64x64 tile each
    const int fr = lane & 15, fk = lane >> 4;

    char* wbase = (char*)lds_ + w * 16384;   // this wave's private 16 KB

    // B fragment byte-offsets within an 8 KB buffer (ki=1 via ^64)
    const int swz = (fk ^ (fr & 7)) << 4;
    int offB[4];
    #pragma unroll
    for (int nf = 0; nf < 4; ++nf)
        offB[nf] = (nf * 16 + fr) * 128 + swz;

    // A: one per-lane base; fragment (m,ki) at byte 96 - m*32 + ki*64 + T*128.
    // srow = (q00 - fr) & 7 is invariant in m, ki, T (all shifts are mult. of 8).
    const short* abase;
    {
        int q00 = 2047 - j0 - wr * 64 + fk * 8 - fr;   // p-index, (m=0,ki=0,T=0)
        int srow = q00 & 7;
        abase = p8 + srow * PROW + (q00 - srow) - 48;  // -96 B rebase
    }

    // B stage source base (per-lane, inverse-swizzled); +65536 shorts per tile
    const short* sbase;
    {
        int h  = (lane & 7) ^ ((lane >> 3) & 7);
        int cg = c0 + wc * 64 + (lane >> 3);
        sbase = vt + ((size_t)(n * NT * 1024 + cg) * 8 + h) * 8;
    }

#define ALOAD(AF, Tq) { \
    const char* _a = (const char*)abase + (size_t)(Tq) * 128; \
    _Pragma("unroll") \
    for (int m = 0; m < 4; ++m) \
        _Pragma("unroll") \
        for (int ki = 0; ki < 2; ++ki) \
            AF[m][ki] = *(const s16x8*)(_a + (96 - m * 32 + ki * 64)); }

#define BREAD(BF, par) { \
    const char* _b = wbase + (par) * 8192; \
    _Pragma("unroll") \
    for (int nf = 0; nf < 4; ++nf) { \
        BF[nf][0] = *(const s16x8*)(_b + offB[nf]); \
        BF[nf][1] = *(const s16x8*)(_b + (offB[nf] ^ 64)); } }

// stage tile TT+2 into this wave's buf[TT&1] (8 x 1 KB, linear dest)
// NOTE: +8 columns per i-step = 64 chunks = 512 shorts (r9 bug: was i*64)
#define STAGE(TT) { \
    const short* _s = sbase + (size_t)((TT) + 2) * 65536; \
    char* _d = wbase + ((TT) & 1) * 8192; \
    _Pragma("unroll") \
    for (int i = 0; i < 8; ++i) \
        gload_lds16(_s + i * 512, _d + i * 1024); }

#define LGKM0() { asm volatile("s_waitcnt lgkmcnt(0)" ::: "memory"); \
                  __builtin_amdgcn_sched_barrier(0); }
#define VMW(NS) { asm volatile("s_waitcnt vmcnt(" NS ")" ::: "memory"); \
                  __builtin_amdgcn_sched_barrier(0); }

#define MFMA_ALL(AF, BF) { \
    __builtin_amdgcn_s_setprio(1); \
    _Pragma("unroll") \
    for (int m = 0; m < 4; ++m) \
        _Pragma("unroll") \
        for (int nf = 0; nf < 4; ++nf) \
            _Pragma("unroll") \
            for (int ki = 0; ki < 2; ++ki) \
                acc[m][nf] = __builtin_amdgcn_mfma_f32_16x16x32_bf16( \
                    AF[m][ki], BF[nf][ki], acc[m][nf], 0, 0, 0); \
    __builtin_amdgcn_s_setprio(0); }

// body T: read B(T), issue A(T+1), retire reads, stage(T+2) over buf[T&1],
// counted wait (A(T)+S(T+1) landed; 16 younger stay in flight), MFMA(T).
#define BODY(TT, CUR, NXT, DOSTAGE, NS) { \
    BREAD(bF, (TT) & 1); \
    ALOAD(NXT, (TT) + 1); \
    LGKM0(); \
    if (DOSTAGE) { STAGE(TT); } \
    VMW(NS); \
    MFMA_ALL(CUR, bF); }

    f32x4 acc[4][4] = {};
    s16x8 afX[4][2], afY[4][2], bF[4][2];

    // ---- prologue: stage tiles 0,1 into bufs 0,1; load A(0) ----
    STAGE(-2);             // tile 0 -> buf0   (-2&1 == 0)
    STAGE(-1);             // tile 1 -> buf1   (-1&1 == 1)
    ALOAD(afX, 0);
    VMW("16");             // S(0) landed (S(1)+A(0) may be in flight)

    for (int T = 0; T < 30; T += 2) {
        BODY(T,     afX, afY, true, "16");
        BODY(T + 1, afY, afX, true, "16");
    }
    BODY(30, afX, afY, false, "8");   // issues A(31) only; S(31) drained
    // tile 31: no further issues
    BREAD(bF, 1);
    LGKM0();
    VMW("0");
    MFMA_ALL(afY, bF);

    // ---- epilogue: C/D layout col=lane&15, row=(lane>>4)*4+r ----
    float* outn = out + (size_t)n * L * HD;
    #pragma unroll
    for (int m = 0; m < 4; ++m) {
        const int row = j0 + wr * 64 + m * 16 + fk * 4;
        #pragma unroll
        for (int nf = 0; nf < 4; ++nf) {
            const int col = c0 + wc * 64 + nf * 16 + fr;
            #pragma unroll
            for (int r = 0; r < 4; ++r)
                outn[(size_t)(row + r) * HD + col] = acc[m][nf][r];
        }
    }
}

extern "C" void kernel_launch(void* const* d_in, const int* in_sizes, int n_in,
                              void* d_out, int out_size, void* d_ws, size_t ws_size,
                              hipStream_t stream) {
    const float* v = (const float*)d_in[0];
    const float* w = (const float*)d_in[1];
    float* out = (float*)d_out;

    short* p8 = (short*)d_ws;                          // 64 KB
    s16x8* vt = (s16x8*)((char*)d_ws + 65536);         // 32 MB

    pb_prep<<<129, 256, 0, stream>>>(w, p8, out + (size_t)NB * L * HD);
    pb_vtile<<<dim3(NT, 4, NB), 256, 0, stream>>>(v, vt);
    pb_gemmw<<<1024, 256, 0, stream>>>(p8, (const short*)vt, out);
}

// Round 11
// 121.634 us; speedup vs baseline: 1.0928x; 1.0928x over previous
//
#include <hip/hip_runtime.h>
#include <hip/hip_bf16.h>

#define L 2048
#define HD 1024   // H*D
#define NB 8      // batch
#define NT 32     // K tiles of BK=64
#define PROW 4096 // p8 row length

using f32x4 = __attribute__((ext_vector_type(4))) float;
using fl4   = __attribute__((ext_vector_type(4))) float;
using s16x8 = __attribute__((ext_vector_type(8))) short;

__device__ __forceinline__ short f2bf(float f) {
    __hip_bfloat16 h = __float2bfloat16(f);
    short s;
    __builtin_memcpy(&s, &h, 2);
    return s;
}

__device__ __forceinline__ void gload_lds16(const void* g, void* l) {
    __builtin_amdgcn_global_load_lds(
        (const __attribute__((address_space(1))) unsigned int*)g,
        (__attribute__((address_space(3))) unsigned int*)l, 16, 0, 0);
}

// ---- fused: p8[s][x] = bf16(p[x+s]) (blocks 0..127) ; z (block 128) ----
__global__ __launch_bounds__(256) void pb_prep(const float* __restrict__ w,
                                               short* __restrict__ p8,
                                               float* __restrict__ z) {
    __shared__ float part[256];
    __shared__ float S[L];
    const int t = threadIdx.x;
    if (blockIdx.x < 128) {
        int idx = blockIdx.x * 256 + t;
        int s = idx >> 12;
        int x = idx & (PROW - 1);
        int k = x + s;
        short val = 0;
        if (k <= 4094) {
            int d = k - 2047; d = d < 0 ? -d : d;
            val = f2bf(w[d]);
        }
        p8[idx] = val;
    } else {
        float loc[8]; float s = 0.f;
        #pragma unroll
        for (int i = 0; i < 8; ++i) { loc[i] = w[t * 8 + i]; s += loc[i]; }
        part[t] = s;
        __syncthreads();
        if (t == 0) {
            float a = 0.f;
            for (int i = 0; i < 256; ++i) { float tmp = part[i]; part[i] = a; a += tmp; }
        }
        __syncthreads();
        float a = part[t];
        #pragma unroll
        for (int i = 0; i < 8; ++i) { a += loc[i]; S[t * 8 + i] = a; }
        __syncthreads();
        const float w0 = S[0];
        #pragma unroll
        for (int i = 0; i < 8; ++i) {
            int j = t * 8 + i;
            z[j] = S[j] + S[2047 - j] - w0;
        }
    }
}

// ---- vt: linear chunk layout. chunk[((n*NT+kk)*1024 + c)*8 + h] (16B) =
//      bf16(v[n][kk*64 + h*8 + j][c]), j=0..7 ----
__global__ __launch_bounds__(256) void pb_vtile(const float* __restrict__ v,
                                                s16x8* __restrict__ vt) {
    // Ts: (c,l) at c*64 + ((lblk ^ ((c>>2)&7))<<3) + lsub  (slot swizzle)
    __shared__ __align__(16) short Ts[256 * 64];   // 32 KB
    const int kk = blockIdx.x, cg4 = blockIdx.y, n = blockIdx.z;
    const int l0 = kk * 64, c0 = cg4 * 256;
    const int t = threadIdx.x;
    const float* vn = v + (size_t)n * L * HD;

    #pragma unroll
    for (int i = 0; i < 16; ++i) {
        int unit = i * 256 + t;          // 4096 units = 64 l x 64 quads
        int l = unit >> 6, cq = unit & 63;
        fl4 x = *(const fl4*)&vn[(size_t)(l0 + l) * HD + c0 + cq * 4];
        int lsub = l & 7, lblk = l >> 3;
        #pragma unroll
        for (int j = 0; j < 4; ++j) {
            int c = cq * 4 + j;
            Ts[c * 64 + ((lblk ^ ((c >> 2) & 7)) << 3) + lsub] = f2bf(x[j]);
        }
    }
    __syncthreads();

    s16x8* outp = vt + ((size_t)(n * NT + kk) * 1024 + c0) * 8;
    #pragma unroll
    for (int i2 = 0; i2 < 8; ++i2) {
        int ci = i2 * 256 + t;           // 2048 chunks (256 c x 8 h)
        int c = ci >> 3, h = ci & 7;
        int slot = h ^ ((c >> 2) & 7);
        outp[ci] = *(const s16x8*)&Ts[c * 64 + slot * 8];
    }
}

// ---- main GEMM: 128x128 tile, BK=64, 4 waves, 2 blocks/CU.
//      B: block-cooperative LDS dbuf (16 KB/buf).  A: DIRECT from the
//      L1-resident p8 table into register double-buffer (no LDS).
//      One __syncthreads per tile. ----
__global__ __launch_bounds__(256, 2) void pb_gemm(const short* __restrict__ p8,
                                                  const short* __restrict__ vt,
                                                  float* __restrict__ out) {
    __shared__ __align__(16) short lds_[16384];  // 32 KB: 2 x 16 KB B buffers

    const int bid = blockIdx.x;
    // XCD affinity: XCD = bid%8 = cm; jm,n peers of one cm share an XCD
    const int cm = bid & 7;
    const int n  = (bid >> 3) & 7;
    const int jm = bid >> 6;
    const int j0 = jm * 128;
    const int c0 = cm * 128;

    const int t = threadIdx.x;
    const int lane = t & 63;
    const int w = t >> 6;                 // wave 0..3
    const int wr = w >> 1, wc = w & 1;    // 2x2 wave grid, 64x64 tile each
    const int fr = lane & 15, fk = lane >> 4;

    // B fragment byte-offsets within a 16 KB buffer (ki=1 via ^64)
    int offB[4];
    #pragma unroll
    for (int nf = 0; nf < 4; ++nf) {
        int c = wc * 64 + nf * 16 + fr;
        offB[nf] = c * 128 + ((fk ^ (c & 7)) << 4);
    }

    // A: one per-lane base into p8; fragment (m,ki,T) at byte
    // 96 - m*32 + ki*64 + T*128.  (validated in r10)
    const short* abase;
    {
        int q00 = 2047 - j0 - wr * 64 + fk * 8 - fr;
        int srow = q00 & 7;
        abase = p8 + srow * PROW + (q00 - srow) - 48;
    }

    // B staging sources (r6-validated): chunk dc = w*256 + i*64 + lane
    const short* srcB0; const short* srcB1; const short* srcB2; const short* srcB3;
    {
        const size_t bbase = ((size_t)(n * NT) * 1024 + c0) * 8ull;
        int dc, c, h;
        dc = w * 256 + 0 * 64 + lane; c = dc >> 3; h = (dc & 7) ^ (c & 7);
        srcB0 = vt + (bbase + (size_t)c * 8 + h) * 8;
        dc = w * 256 + 1 * 64 + lane; c = dc >> 3; h = (dc & 7) ^ (c & 7);
        srcB1 = vt + (bbase + (size_t)c * 8 + h) * 8;
        dc = w * 256 + 2 * 64 + lane; c = dc >> 3; h = (dc & 7) ^ (c & 7);
        srcB2 = vt + (bbase + (size_t)c * 8 + h) * 8;
        dc = w * 256 + 3 * 64 + lane; c = dc >> 3; h = (dc & 7) ^ (c & 7);
        srcB3 = vt + (bbase + (size_t)c * 8 + h) * 8;
    }
    const int wB = w * 4096;              // wave-uniform dest base (bytes)

#define STAGE_B(par) { \
    char* _d = (char*)lds_ + (par) * 16384 + wB; \
    gload_lds16(srcB0, _d); \
    gload_lds16(srcB1, _d + 1024); \
    gload_lds16(srcB2, _d + 2048); \
    gload_lds16(srcB3, _d + 3072); \
    srcB0 += 65536; srcB1 += 65536; srcB2 += 65536; srcB3 += 65536; }

#define ALOAD(AF, Tq) { \
    const char* _a = (const char*)abase + (size_t)(Tq) * 128; \
    _Pragma("unroll") \
    for (int m = 0; m < 4; ++m) \
        _Pragma("unroll") \
        for (int ki = 0; ki < 2; ++ki) \
            AF[m][ki] = *(const s16x8*)(_a + (96 - m * 32 + ki * 64)); }

#define BREAD(BF, par) { \
    const char* _b = (const char*)lds_ + (par) * 16384; \
    _Pragma("unroll") \
    for (int nf = 0; nf < 4; ++nf) { \
        BF[nf][0] = *(const s16x8*)(_b + offB[nf]); \
        BF[nf][1] = *(const s16x8*)(_b + (offB[nf] ^ 64)); } }

#define MFMA_ALL(AF, BF) { \
    __builtin_amdgcn_s_setprio(1); \
    _Pragma("unroll") \
    for (int m = 0; m < 4; ++m) \
        _Pragma("unroll") \
        for (int nf = 0; nf < 4; ++nf) \
            _Pragma("unroll") \
            for (int ki = 0; ki < 2; ++ki) \
                acc[m][nf] = __builtin_amdgcn_mfma_f32_16x16x32_bf16( \
                    AF[m][ki], BF[nf][ki], acc[m][nf], 0, 0, 0); \
    __builtin_amdgcn_s_setprio(0); }

// body T: stage B(T+1) into buf[(T+1)&1], issue A(T+1)->NXT regs,
// read B(T) frags from buf[T&1], MFMA with CUR regs, tile barrier.
// The __syncthreads' vmcnt(0)+lgkm(0) drain retires S(T+1)+A(T+1)
// (issued ~a full body earlier by the time of the NEXT body's use).
#define BODY(TT, CUR, NXT, DOSTAGE) { \
    if (DOSTAGE) { STAGE_B(((TT) + 1) & 1); ALOAD(NXT, (TT) + 1); } \
    BREAD(bF, (TT) & 1); \
    MFMA_ALL(CUR, bF); \
    __syncthreads(); }

    f32x4 acc[4][4] = {};
    s16x8 afX[4][2], afY[4][2], bF[4][2];

    // ---- prologue: stage B(0) into buf0, load A(0) ----
    STAGE_B(0);
    ALOAD(afX, 0);
    __syncthreads();   // drains S(0)+A(0)

    for (int T = 0; T < 30; T += 2) {
        BODY(T,     afX, afY, true);
        BODY(T + 1, afY, afX, true);
    }
    BODY(30, afX, afY, true);     // stages B(31), loads A(31)->afY
    // tile 31: no further staging
    BREAD(bF, 1);
    MFMA_ALL(afY, bF);

    // ---- epilogue: C/D layout col=lane&15, row=(lane>>4)*4+r ----
    float* outn = out + (size_t)n * L * HD;
    #pragma unroll
    for (int m = 0; m < 4; ++m) {
        const int row = j0 + wr * 64 + m * 16 + fk * 4;
        #pragma unroll
        for (int nf = 0; nf < 4; ++nf) {
            const int col = c0 + wc * 64 + nf * 16 + fr;
            #pragma unroll
            for (int r = 0; r < 4; ++r)
                outn[(size_t)(row + r) * HD + col] = acc[m][nf][r];
        }
    }
}

extern "C" void kernel_launch(void* const* d_in, const int* in_sizes, int n_in,
                              void* d_out, int out_size, void* d_ws, size_t ws_size,
                              hipStream_t stream) {
    const float* v = (const float*)d_in[0];
    const float* w = (const float*)d_in[1];
    float* out = (float*)d_out;

    short* p8 = (short*)d_ws;                          // 64 KB
    s16x8* vt = (s16x8*)((char*)d_ws + 65536);         // 32 MB

    pb_prep<<<129, 256, 0, stream>>>(w, p8, out + (size_t)NB * L * HD);
    pb_vtile<<<dim3(NT, 4, NB), 256, 0, stream>>>(v, vt);
    pb_gemm<<<1024, 256, 0, stream>>>(p8, (const short*)vt, out);
}